// Round 13
// baseline (465.562 us; speedup 1.0000x reference)
//
#include <hip/hip_runtime.h>

// ---------------------------------------------------------------------------
// UnetMACReconNet: modulated-conv UNet + IN/ReLU + FFT data consistency
// Round 13: batched 9-tap A-fragment prefetch (aT[9]) for NCOG<=2 convs —
//           forces 9 concurrent global loads instead of the serial
//           load->wait->MFMA chain the compiler emitted at VGPR=20.
// ---------------------------------------------------------------------------

#define EPS_IN 1e-5f
constexpr int STST = 7936;   // float2 stride between stat buckets

typedef __attribute__((ext_vector_type(8))) short short8;
typedef __attribute__((ext_vector_type(4))) short short4_t;
typedef __attribute__((ext_vector_type(4))) float f32x4;

__device__ __forceinline__ short f2bf(float f) {
    unsigned u = __float_as_uint(f);
    unsigned r = (u + 0x7fffu + ((u >> 16) & 1u)) >> 16;
    return (short)r;
}
__device__ __forceinline__ float bf2f(short s) {
    return __uint_as_float(((unsigned)(unsigned short)s) << 16);
}

// ---------------- fused setup: modded weights + eff1x1 + stat zeroing -------
struct SetupJobs {
    const float* W[8];
    const float* mod[8];
    short* wm[8];
    int Co[8];
    int Ci[8];
    int cum[9];
    const float *w1, *b1, *w2, *b2, *w3, *b3;
    float* eff;
    float* stats;
    int statN;
    int wmBlocks;
};

__global__ void setup_all(SetupJobs j)
{
    const int bx = blockIdx.x, tid = threadIdx.x;
    if (bx < j.wmBlocks) {
        int idx = bx * 256 + tid;
        if (idx >= j.cum[8]) return;
        int l = 0;
        while (idx >= j.cum[l + 1]) ++l;
        int local = idx - j.cum[l];
        const int Ci = j.Ci[l], Co = j.Co[l];
        int ci = local % Ci;
        int rem = local / Ci;
        int co = rem % Co;
        int b = rem / Co;
        const float* wp = j.W[l] + (size_t)(co * Ci + ci) * 9;
        const float* mp = j.mod[l] + ((size_t)((size_t)b * Co + co) * Ci + ci) * 9;
        short* wm = j.wm[l];
#pragma unroll
        for (int k = 0; k < 9; ++k)
            wm[(((size_t)(b * 9 + k) * Co + co) * Ci + ci)] = f2bf(wp[k] * mp[k]);
    } else if (bx == j.wmBlocks) {
        if (tid < 32) {
            float s = 0.f;
            for (int k = 0; k < 16; ++k) s += j.w2[k] * j.w1[k * 32 + tid];
            j.eff[tid] = j.w3[0] * s;
        }
        if (tid == 32) {
            float s = 0.f;
            for (int k = 0; k < 16; ++k) s += j.w2[k] * j.b1[k];
            j.eff[32] = j.w3[0] * (s + j.b2[0]) + j.b3[0];
        }
    } else {
        int i = (bx - j.wmBlocks - 1) * 256 + tid;
        if (i < j.statN) j.stats[i] = 0.f;
    }
}

// ---------------- MFMA conv3x3, CL, fused IN-stats; optional fused upsample -
template <int VR, int NCOG, bool UP>
__global__ __launch_bounds__(256) void conv3x3_cl(
    const short* __restrict__ x1, int Ci1,
    const short* __restrict__ x2,
    const float2* __restrict__ st1, float invHW1,
    const short* __restrict__ wm,   // [b][9][Co][Ci] bf16
    short* __restrict__ y,
    float2* __restrict__ stats,
    int Ci, int Co, int H, int W)
{
    constexpr int TH = 4 * VR, SH = TH + 2, SW = 18;
    constexpr int STN = UP ? 128 : 1;
    constexpr int LH = UP ? (TH / 2 + 2) : 1;
    constexpr int LW = 10, LRW = LW * 8;
    constexpr bool DW = (TH * 16 * NCOG * 16) <= (SH * SW * 32);
    __shared__ __align__(16) short s_x[SH][SW][32];
    __shared__ float s_red[4][4][NCOG][4][2];
    __shared__ float2 s_st1[STN];
    __shared__ __align__(16) short s_lr[UP ? 4 : 1][LH][LRW];

    const int tid = threadIdx.x;
    const int lane = tid & 63, wv = tid >> 6;
    const int m = lane & 15, g = lane >> 4;

    const int b = blockIdx.x & 7;
    int r = blockIdx.x >> 3;
    const int nCoB = Co / (16 * NCOG);
    const int coblk = r % nCoB;
    const int tileId = r / nCoB;
    const int tilesx = W >> 4;
    const int tx0 = (tileId % tilesx) * 16;
    const int ty0 = (tileId / tilesx) * TH;
    const int co0 = coblk * (16 * NCOG);
    const int Ci2 = Ci - Ci1;
    const int Hs = H >> 1, Ws = W >> 1;
    const int bucket = tileId & 7;

    if (UP) {
        for (int i = tid; i < Ci1; i += 256) {
            float sx = 0.f, sy = 0.f;
#pragma unroll
            for (int k = 0; k < 8; ++k) {
                float2 v = st1[(size_t)k * STST + (size_t)b * Ci1 + i];
                sx += v.x; sy += v.y;
            }
            float mu = sx * invHW1;
            float var = sy * invHW1 - mu * mu;
            s_st1[i] = make_float2(mu, rsqrtf(var + EPS_IN));
        }
    }

    f32x4 acc[NCOG][VR];
#pragma unroll
    for (int cg = 0; cg < NCOG; ++cg)
#pragma unroll
        for (int rr = 0; rr < VR; ++rr) acc[cg][rr] = (f32x4)0.f;

    const short* wmb = wm + (size_t)b * 9 * Co * Ci;
    const short* x1b = x1 + (size_t)b * (UP ? (size_t)Hs * Ws : (size_t)H * W) * Ci1;
    const short* x2b = x2 + (size_t)b * H * W * Ci2;

    for (int ci0 = 0; ci0 < Ci; ci0 += 32) {
        __syncthreads();
        if (UP && ci0 < Ci1) {
            const int cb = ci0;
            const int ly0 = (ty0 >> 1) - 1, lx0 = (tx0 >> 1) - 1;
            for (int i2 = tid; i2 < 4 * LH * LW; i2 += 256) {
                int gg = i2 & 3, p2 = i2 >> 2;
                int jj = p2 / LW, ii = p2 - jj * LW;
                int sy2 = ly0 + jj; sy2 = sy2 < 0 ? 0 : (sy2 >= Hs ? Hs - 1 : sy2);
                int sx2 = lx0 + ii; sx2 = sx2 < 0 ? 0 : (sx2 >= Ws ? Ws - 1 : sx2);
                short8 v = *(const short8*)(x1b + ((size_t)sy2 * Ws + sx2) * Ci1 + cb + gg * 8);
                short8 o;
#pragma unroll
                for (int e = 0; e < 8; ++e) {
                    float2 sv = s_st1[cb + gg * 8 + e];
                    o[e] = f2bf(fmaxf(0.f, (bf2f(v[e]) - sv.x) * sv.y));
                }
                *(short8*)&s_lr[gg][jj][ii * 8] = o;
            }
            __syncthreads();
            for (int idx = tid; idx < SH * SW * 4; idx += 256) {
                int gg = idx & 3, pos = idx >> 2;
                int yy = pos / SW, xx = pos - yy * SW;
                int gy = ty0 + yy - 1, gx = tx0 + xx - 1;
                short8 v = (short8)0;
                if (gy >= 0 && gy < H && gx >= 0 && gx < W) {
                    int xk = gx >> 1, yk = gy >> 1;
                    int xo = gx & 1, yo = gy & 1;
                    int xa = xo ? xk : (xk > 0 ? xk - 1 : 0);
                    int xb = xo ? (xk + 1 < Ws ? xk + 1 : Ws - 1) : xk;
                    float wxa = xo ? 0.75f : 0.25f;
                    int ya = yo ? yk : (yk > 0 ? yk - 1 : 0);
                    int yb = yo ? (yk + 1 < Hs ? yk + 1 : Hs - 1) : yk;
                    float wya = yo ? 0.75f : 0.25f;
                    int ja = ya - ly0, jb = yb - ly0;
                    int ia = xa - lx0, ib2 = xb - lx0;
                    short8 vaa = *(const short8*)&s_lr[gg][ja][ia * 8];
                    short8 vab = *(const short8*)&s_lr[gg][ja][ib2 * 8];
                    short8 vba = *(const short8*)&s_lr[gg][jb][ia * 8];
                    short8 vbb = *(const short8*)&s_lr[gg][jb][ib2 * 8];
#pragma unroll
                    for (int e = 0; e < 8; ++e) {
                        float r0 = wxa * bf2f(vaa[e]) + (1.f - wxa) * bf2f(vab[e]);
                        float r1 = wxa * bf2f(vba[e]) + (1.f - wxa) * bf2f(vbb[e]);
                        v[e] = f2bf(wya * r0 + (1.f - wya) * r1);
                    }
                }
                *(short8*)&s_x[yy][xx][(gg ^ (xx & 3)) * 8] = v;
            }
        } else {
            const short* src; int C, cb;
            if (ci0 < Ci1) { src = x1b; C = Ci1; cb = ci0; }
            else           { src = x2b; C = Ci2; cb = ci0 - Ci1; }
            for (int idx = tid; idx < SH * SW * 4; idx += 256) {
                int gg = idx & 3, pos = idx >> 2;
                int yy = pos / SW, xx = pos - yy * SW;
                int gy = ty0 + yy - 1, gx = tx0 + xx - 1;
                short8 v = (short8)0;
                if (gy >= 0 && gy < H && gx >= 0 && gx < W)
                    v = *(const short8*)(src + ((size_t)gy * W + gx) * C + cb + gg * 8);
                *(short8*)&s_x[yy][xx][(gg ^ (xx & 3)) * 8] = v;
            }
        }
        __syncthreads();

        if constexpr (NCOG <= 2) {
            // ---- batched A prefetch: 9 tap loads in flight per co-group
#pragma unroll
            for (int cg = 0; cg < NCOG; ++cg) {
                short8 aT[9];
#pragma unroll
                for (int t = 0; t < 9; ++t)
                    aT[t] = *(const short8*)(wmb + ((size_t)t * Co + co0 + cg * 16 + m) * Ci + ci0 + g * 8);
#pragma unroll
                for (int t = 0; t < 9; ++t) {
                    const int dy = t / 3, dx = t - 3 * (t / 3);
                    const int xx = m + dx;
                    const int sgo = (g ^ (xx & 3)) * 8;
#pragma unroll
                    for (int rr = 0; rr < VR; ++rr) {
                        short8 bf = *(const short8*)&s_x[wv * VR + rr + dy][xx][sgo];
                        acc[cg][rr] = __builtin_amdgcn_mfma_f32_16x16x32_bf16(aT[t], bf, acc[cg][rr], 0, 0, 0);
                    }
                }
            }
        } else {
#pragma unroll
            for (int t = 0; t < 9; ++t) {
                const int dy = t / 3, dx = t - 3 * (t / 3);
                const short* wr = wmb + ((size_t)t * Co + co0) * Ci + ci0 + g * 8;
                short8 a[NCOG];
#pragma unroll
                for (int cg = 0; cg < NCOG; ++cg)
                    a[cg] = *(const short8*)(wr + (size_t)(cg * 16 + m) * Ci);
                const int xx = m + dx;
                const int sgo = (g ^ (xx & 3)) * 8;
#pragma unroll
                for (int rr = 0; rr < VR; ++rr) {
                    short8 bf = *(const short8*)&s_x[wv * VR + rr + dy][xx][sgo];
#pragma unroll
                    for (int cg = 0; cg < NCOG; ++cg)
                        acc[cg][rr] = __builtin_amdgcn_mfma_f32_16x16x32_bf16(a[cg], bf, acc[cg][rr], 0, 0, 0);
                }
            }
        }
    }

    // ---- writeout
    if constexpr (DW) {
        __syncthreads();
        short* sd = (short*)&s_x[0][0][0];   // [TH][16][NCOG*16]
#pragma unroll
        for (int cg = 0; cg < NCOG; ++cg)
#pragma unroll
            for (int rr = 0; rr < VR; ++rr) {
                short4_t o;
#pragma unroll
                for (int q = 0; q < 4; ++q) o[q] = f2bf(acc[cg][rr][q]);
                *(short4_t*)&sd[((wv * VR + rr) * 16 + m) * (NCOG * 16) + cg * 16 + g * 4] = o;
            }
        __syncthreads();
        constexpr int N16 = TH * 16 * NCOG * 2;
        constexpr int CPR = NCOG * 32;
        for (int c = tid; c < N16; c += 256) {
            int row = c / CPR;
            int o16 = c % CPR;
            int p = o16 / (NCOG * 2);
            int cw = o16 % (NCOG * 2);
            short8 v = *(short8*)&sd[(row * 16 + p) * (NCOG * 16) + cw * 8];
            *(short8*)(y + (((size_t)b * H + ty0 + row) * W + tx0 + p) * Co + co0 + cw * 8) = v;
        }
    } else {
        const int ox = tx0 + m;
#pragma unroll
        for (int cg = 0; cg < NCOG; ++cg)
#pragma unroll
            for (int rr = 0; rr < VR; ++rr) {
                int oy = ty0 + wv * VR + rr;
                short4_t o;
#pragma unroll
                for (int q = 0; q < 4; ++q) o[q] = f2bf(acc[cg][rr][q]);
                *(short4_t*)(y + (((size_t)b * H + oy) * W + ox) * Co + co0 + cg * 16 + g * 4) = o;
            }
    }

    // ---- fused stats (bucketed atomics)
#pragma unroll
    for (int cg = 0; cg < NCOG; ++cg)
#pragma unroll
        for (int q = 0; q < 4; ++q) {
            float s = 0.f, s2 = 0.f;
#pragma unroll
            for (int rr = 0; rr < VR; ++rr) { float v = acc[cg][rr][q]; s += v; s2 += v * v; }
#pragma unroll
            for (int msk = 1; msk < 16; msk <<= 1) { s += __shfl_xor(s, msk); s2 += __shfl_xor(s2, msk); }
            if (m == 0) { s_red[wv][g][cg][q][0] = s; s_red[wv][g][cg][q][1] = s2; }
        }
    __syncthreads();
    for (int i = tid; i < 16 * NCOG; i += 256) {
        int q = i & 3, gg = (i >> 2) & 3, cg = i >> 4;
        float S = 0.f, S2 = 0.f;
#pragma unroll
        for (int w = 0; w < 4; ++w) { S += s_red[w][gg][cg][q][0]; S2 += s_red[w][gg][cg][q][1]; }
        float* sp = (float*)&stats[(size_t)bucket * STST + (size_t)b * Co + co0 + i];
        atomicAdd(sp, S); atomicAdd(sp + 1, S2);
    }
}

// ---------------- d0 conv: Ci=1, Co=32, fp32 NCHW in -> CL bf16 raw out -----
__global__ __launch_bounds__(256) void conv_d0_cl(
    const float* __restrict__ x0, const float* __restrict__ W,
    const float* __restrict__ mod, short* __restrict__ y,
    float2* __restrict__ stats)
{
    __shared__ float s[18][18];
    __shared__ float sw[32][9];
    __shared__ float s_red[8][32][2];
    __shared__ __align__(16) short sd[16][16][32];
    const int tid = threadIdx.x;
    const int tx = tid & 15, ty = tid >> 4;
    const int tx0 = (blockIdx.x & 15) * 16, ty0 = (blockIdx.x >> 4) * 16;
    const int b = blockIdx.y;
    if (tid < 288) sw[tid / 9][tid % 9] = W[tid] * mod[b * 288 + tid];
    for (int pos = tid; pos < 18 * 18; pos += 256) {
        int yy = pos / 18, xx = pos - yy * 18;
        int gy = ty0 + yy - 1, gx = tx0 + xx - 1;
        bool inb = gy >= 0 && gy < 256 && gx >= 0 && gx < 256;
        s[yy][xx] = inb ? x0[((size_t)b << 16) + gy * 256 + gx] : 0.f;
    }
    __syncthreads();
    float v[3][3];
#pragma unroll
    for (int r = 0; r < 3; ++r)
#pragma unroll
        for (int c = 0; c < 3; ++c) v[r][c] = s[ty + r][tx + c];
    float vals[32];
#pragma unroll
    for (int co = 0; co < 32; ++co) {
        float a = 0.f;
#pragma unroll
        for (int r = 0; r < 3; ++r)
#pragma unroll
            for (int c = 0; c < 3; ++c) a = fmaf(v[r][c], sw[co][r * 3 + c], a);
        vals[co] = a;
    }
#pragma unroll
    for (int j = 0; j < 4; ++j) {
        short8 o;
#pragma unroll
        for (int e = 0; e < 8; ++e) o[e] = f2bf(vals[j * 8 + e]);
        *(short8*)&sd[ty][tx][j * 8] = o;
    }
    __syncthreads();
    for (int c = tid; c < 1024; c += 256) {
        int row = c >> 6, o = c & 63;
        short8 vv = *(short8*)&sd[row][o >> 2][(o & 3) * 8];
        *(short8*)(y + (((size_t)b * 256 + ty0 + row) * 256 + tx0 + (o >> 2)) * 32 + (o & 3) * 8) = vv;
    }
    {
        const int c = tid & 31, grp = tid >> 5;
        const short* sdf = (const short*)sd;
        float ss = 0.f, ss2 = 0.f;
#pragma unroll
        for (int p = 0; p < 32; ++p) {
            float vv = bf2f(sdf[(grp * 32 + p) * 32 + c]);
            ss += vv; ss2 += vv * vv;
        }
        s_red[grp][c][0] = ss;
        s_red[grp][c][1] = ss2;
    }
    __syncthreads();
    if (tid < 32) {
        float S = 0.f, S2 = 0.f;
#pragma unroll
        for (int g2 = 0; g2 < 8; ++g2) { S += s_red[g2][tid][0]; S2 += s_red[g2][tid][1]; }
        int bucket = blockIdx.x & 7;
        float* sp = (float*)&stats[(size_t)bucket * STST + (size_t)b * 32 + tid];
        atomicAdd(sp, S); atomicAdd(sp + 1, S2);
    }
}

// ---------------- 2x2 maxpool + fused norm/relu + normalized skip writeback -
__global__ __launch_bounds__(256) void maxpool_cl(
    short* __restrict__ in, const float2* __restrict__ st, float invHW,
    short* __restrict__ out, int c8s, int ws, int hs, int total8)
{
    const int C = 8 << c8s;
    __shared__ float2 sst[2048];
    for (int i = threadIdx.x; i < 8 * C; i += 256) {
        int bb = i / C, c = i % C;
        float sx = 0.f, sy = 0.f;
#pragma unroll
        for (int k = 0; k < 8; ++k) {
            float2 v = st[(size_t)k * STST + (size_t)bb * C + c];
            sx += v.x; sy += v.y;
        }
        float mu = sx * invHW;
        sst[i] = make_float2(mu, rsqrtf(sy * invHW - mu * mu + EPS_IN));
    }
    __syncthreads();
    for (int idx = blockIdx.x * 256 + threadIdx.x; idx < total8; idx += gridDim.x * 256) {
        int c8 = idx & ((1 << c8s) - 1);
        int p = idx >> c8s;
        int x = p & ((1 << ws) - 1);
        int yy = (p >> ws) & ((1 << hs) - 1);
        int b = p >> (ws + hs);
        short* ip = in + (((size_t)b * (2 << hs) + 2 * yy) * (2 << ws) + 2 * x) * C + c8 * 8;
        size_t rs = (size_t)(2 << ws) * C;
        short8 v0 = *(const short8*)ip, v1 = *(const short8*)(ip + C);
        short8 v2 = *(const short8*)(ip + rs), v3 = *(const short8*)(ip + rs + C);
        short8 o, w0, w1, w2, w3;
#pragma unroll
        for (int e = 0; e < 8; ++e) {
            float2 sv = sst[b * C + c8 * 8 + e];
            float n0 = fmaxf(0.f, (bf2f(v0[e]) - sv.x) * sv.y);
            float n1 = fmaxf(0.f, (bf2f(v1[e]) - sv.x) * sv.y);
            float n2 = fmaxf(0.f, (bf2f(v2[e]) - sv.x) * sv.y);
            float n3 = fmaxf(0.f, (bf2f(v3[e]) - sv.x) * sv.y);
            w0[e] = f2bf(n0); w1[e] = f2bf(n1); w2[e] = f2bf(n2); w3[e] = f2bf(n3);
            o[e] = f2bf(fmaxf(fmaxf(n0, n1), fmaxf(n2, n3)));
        }
        *(short8*)ip = w0;
        *(short8*)(ip + C) = w1;
        *(short8*)(ip + rs) = w2;
        *(short8*)(ip + rs + C) = w3;
        *(short8*)(out + (size_t)idx * 8) = o;
    }
}

// ---------------- bilinear 2x upsample + fused norm/relu (u0 source only) ---
__global__ __launch_bounds__(256) void upsample_cl(
    const short* __restrict__ in, const float2* __restrict__ st, float invHW,
    short* __restrict__ out, int c8s, int wsi, int hsi, int total8)
{
    const int C = 8 << c8s;
    const int Win = 1 << wsi, Hin = 1 << hsi;
    __shared__ float2 sst[2048];
    for (int i = threadIdx.x; i < 8 * C; i += 256) {
        int bb = i / C, c = i % C;
        float sx = 0.f, sy = 0.f;
#pragma unroll
        for (int k = 0; k < 8; ++k) {
            float2 v = st[(size_t)k * STST + (size_t)bb * C + c];
            sx += v.x; sy += v.y;
        }
        float mu = sx * invHW;
        sst[i] = make_float2(mu, rsqrtf(sy * invHW - mu * mu + EPS_IN));
    }
    __syncthreads();
    for (int idx = blockIdx.x * 256 + threadIdx.x; idx < total8; idx += gridDim.x * 256) {
        int c8 = idx & ((1 << c8s) - 1);
        int p = idx >> c8s;
        int x = p & (2 * Win - 1);
        int yy = (p >> (wsi + 1)) & (2 * Hin - 1);
        int b = p >> (wsi + 1 + hsi + 1);
        int xk = x >> 1, yk = yy >> 1;
        int xa, xb; float wxa;
        if (x & 1) { xa = xk; xb = (xk + 1 < Win) ? xk + 1 : Win - 1; wxa = 0.75f; }
        else       { xa = (xk > 0) ? xk - 1 : 0; xb = xk; wxa = 0.25f; }
        int ya, yb; float wya;
        if (yy & 1) { ya = yk; yb = (yk + 1 < Hin) ? yk + 1 : Hin - 1; wya = 0.75f; }
        else        { ya = (yk > 0) ? yk - 1 : 0; yb = yk; wya = 0.25f; }
        const short* ib = in + (size_t)b * Hin * Win * C + c8 * 8;
        short8 vaa = *(const short8*)(ib + ((size_t)ya * Win + xa) * C);
        short8 vab = *(const short8*)(ib + ((size_t)ya * Win + xb) * C);
        short8 vba = *(const short8*)(ib + ((size_t)yb * Win + xa) * C);
        short8 vbb = *(const short8*)(ib + ((size_t)yb * Win + xb) * C);
        short8 o;
#pragma unroll
        for (int e = 0; e < 8; ++e) {
            float2 sv = sst[b * C + c8 * 8 + e];
            float aa = fmaxf(0.f, (bf2f(vaa[e]) - sv.x) * sv.y);
            float ab = fmaxf(0.f, (bf2f(vab[e]) - sv.x) * sv.y);
            float ba = fmaxf(0.f, (bf2f(vba[e]) - sv.x) * sv.y);
            float bb = fmaxf(0.f, (bf2f(vbb[e]) - sv.x) * sv.y);
            float r0 = wxa * aa + (1.f - wxa) * ab;
            float r1 = wxa * ba + (1.f - wxa) * bb;
            o[e] = f2bf(wya * r0 + (1.f - wya) * r1);
        }
        *(short8*)(out + (size_t)idx * 8) = o;
    }
}

// ---------------- 256-point radix-2 FFT in LDS (one wave) -------------------
__device__ __forceinline__ void fft256(float2* s, int tid, float sign)
{
    __syncthreads();
#pragma unroll
    for (int t = 0; t < 4; ++t) {
        int i = tid + t * 64;
        int r = __brev(i) >> 24;
        if (r > i) { float2 tmp = s[i]; s[i] = s[r]; s[r] = tmp; }
    }
    __syncthreads();
    for (int st = 1; st <= 8; ++st) {
        int m = 1 << st, half = m >> 1;
#pragma unroll
        for (int t = 0; t < 2; ++t) {
            int k = tid + t * 64;
            int g = k >> (st - 1), j = k & (half - 1);
            int i0 = (g << st) + j, i1 = i0 + half;
            float ang = sign * 6.283185307179586f * (float)j / (float)m;
            float sn, cs;
            __sincosf(ang, &sn, &cs);
            float2 a = s[i0], b = s[i1];
            float2 tt = make_float2(b.x * cs - b.y * sn, b.x * sn + b.y * cs);
            s[i0] = make_float2(a.x + tt.x, a.y + tt.y);
            s[i1] = make_float2(a.x - tt.x, a.y - tt.y);
        }
        __syncthreads();
    }
}

// ---------------- fused: norm(u3) + 1x1 chain + residual + row FFT ----------
__global__ __launch_bounds__(64) void final_fft_rows(
    const short* __restrict__ act, const float2* __restrict__ st, float invHW,
    const float* __restrict__ x0, const float* __restrict__ eff,
    float2* __restrict__ cplx)
{
    __shared__ float2 s[256];
    __shared__ float2 sst[32];
    __shared__ float seff[33];
    const int row = blockIdx.x, tid = threadIdx.x;
    const int b = row >> 8, yy = row & 255;
    if (tid < 32) {
        float sx = 0.f, sy = 0.f;
#pragma unroll
        for (int k = 0; k < 8; ++k) {
            float2 v = st[(size_t)k * STST + (size_t)b * 32 + tid];
            sx += v.x; sy += v.y;
        }
        float mu = sx * invHW;
        sst[tid] = make_float2(mu, rsqrtf(sy * invHW - mu * mu + EPS_IN));
    }
    if (tid < 33) seff[tid] = eff[tid];
    __syncthreads();
#pragma unroll
    for (int k = 0; k < 4; ++k) {
        int x = k * 64 + tid;
        const short8* a = (const short8*)(act + (((size_t)b * 256 + yy) * 256 + x) * 32);
        float sacc = seff[32] + x0[((size_t)b << 16) + (yy << 8) + x];
#pragma unroll
        for (int j = 0; j < 4; ++j) {
            short8 v = a[j];
#pragma unroll
            for (int e = 0; e < 8; ++e) {
                float2 sv = sst[j * 8 + e];
                sacc += seff[j * 8 + e] * fmaxf(0.f, (bf2f(v[e]) - sv.x) * sv.y);
            }
        }
        s[x] = make_float2(sacc, 0.f);
    }
    fft256(s, tid, -1.f);
    float2* o = cplx + (size_t)row * 256;
    for (int i = tid; i < 256; i += 64) o[i] = s[i];
}

// ---------------- column FFT + combine: 8 columns per 256-thread block ------
__global__ __launch_bounds__(256) void fft_cols_combine8(
    float2* __restrict__ data, const float* __restrict__ ksp,
    const float* __restrict__ mask)
{
    __shared__ float2 s2[8][260];
    const int tid = threadIdx.x;
    const int b = blockIdx.x >> 5;
    const int col0 = (blockIdx.x & 31) * 8;
    float2* base = data + (size_t)b * 65536 + col0;
    for (int idx = tid; idx < 2048; idx += 256) {
        int row = idx >> 3, c = idx & 7;
        s2[c][row] = base[row * 256 + c];
    }
    __syncthreads();
    const int c = tid >> 5, lt = tid & 31;
#pragma unroll
    for (int t = 0; t < 8; ++t) {
        int i = lt + t * 32;
        int r = __brev(i) >> 24;
        if (r > i) { float2 tmp = s2[c][i]; s2[c][i] = s2[c][r]; s2[c][r] = tmp; }
    }
    __syncthreads();
    for (int st = 1; st <= 8; ++st) {
        int m = 1 << st, half = m >> 1;
#pragma unroll
        for (int t = 0; t < 4; ++t) {
            int k = lt + t * 32;
            int g = k >> (st - 1), j = k & (half - 1);
            int i0 = (g << st) + j, i1 = i0 + half;
            float ang = -6.283185307179586f * (float)j / (float)m;
            float sn, cs;
            __sincosf(ang, &sn, &cs);
            float2 a = s2[c][i0], bb = s2[c][i1];
            float2 tt = make_float2(bb.x * cs - bb.y * sn, bb.x * sn + bb.y * cs);
            s2[c][i0] = make_float2(a.x + tt.x, a.y + tt.y);
            s2[c][i1] = make_float2(a.x - tt.x, a.y - tt.y);
        }
        __syncthreads();
    }
    for (int idx = tid; idx < 2048; idx += 256) {
        int row = idx >> 3, cc = idx & 7;
        size_t mi = ((size_t)b * 256 + row) * 256 + col0 + cc;
        float mval = mask[mi];
        float2 kp = s2[cc][row];
        float kr = ksp[mi * 2], ki = ksp[mi * 2 + 1];
        s2[cc][row] = make_float2(mval * kr + (1.f - mval) * kp.x * (1.f / 256.f),
                                  mval * ki + (1.f - mval) * kp.y * (1.f / 256.f));
    }
    __syncthreads();
#pragma unroll
    for (int t = 0; t < 8; ++t) {
        int i = lt + t * 32;
        int r = __brev(i) >> 24;
        if (r > i) { float2 tmp = s2[c][i]; s2[c][i] = s2[c][r]; s2[c][r] = tmp; }
    }
    __syncthreads();
    for (int st = 1; st <= 8; ++st) {
        int m = 1 << st, half = m >> 1;
#pragma unroll
        for (int t = 0; t < 4; ++t) {
            int k = lt + t * 32;
            int g = k >> (st - 1), j = k & (half - 1);
            int i0 = (g << st) + j, i1 = i0 + half;
            float ang = 6.283185307179586f * (float)j / (float)m;
            float sn, cs;
            __sincosf(ang, &sn, &cs);
            float2 a = s2[c][i0], bb = s2[c][i1];
            float2 tt = make_float2(bb.x * cs - bb.y * sn, bb.x * sn + bb.y * cs);
            s2[c][i0] = make_float2(a.x + tt.x, a.y + tt.y);
            s2[c][i1] = make_float2(a.x - tt.x, a.y - tt.y);
        }
        __syncthreads();
    }
    for (int idx = tid; idx < 2048; idx += 256) {
        int row = idx >> 3, cc = idx & 7;
        base[row * 256 + cc] = s2[cc][row];
    }
}

__global__ __launch_bounds__(64) void fft_rows_inv(const float2* __restrict__ data,
                                                   float* __restrict__ out)
{
    __shared__ float2 s[256];
    int row = blockIdx.x, tid = threadIdx.x;
    const float2* p = data + (size_t)row * 256;
    for (int i = tid; i < 256; i += 64) s[i] = p[i];
    fft256(s, tid, 1.f);
    float* o = out + (size_t)row * 256;
    for (int i = tid; i < 256; i += 64) o[i] = s[i].x * (1.f / 256.f);
}

// ---------------------------------------------------------------------------
extern "C" void kernel_launch(void* const* d_in, const int* in_sizes, int n_in,
                              void* d_out, int out_size, void* d_ws, size_t ws_size,
                              hipStream_t stream)
{
    (void)in_sizes; (void)n_in; (void)out_size; (void)ws_size;

    const float* x0 = (const float*)d_in[0];
    const float* ksp = (const float*)d_in[1];
    const float* mask = (const float*)d_in[2];
    const float* mod_d[4] = {(const float*)d_in[3], (const float*)d_in[6],
                             (const float*)d_in[9], (const float*)d_in[12]};
    const float* W_d[4] = {(const float*)d_in[4], (const float*)d_in[7],
                           (const float*)d_in[10], (const float*)d_in[13]};
    const float* mod_lat = (const float*)d_in[15];
    const float* W_lat = (const float*)d_in[16];
    const float* mod_u[4] = {(const float*)d_in[18], (const float*)d_in[21],
                             (const float*)d_in[24], (const float*)d_in[27]};
    const float* W_u[4] = {(const float*)d_in[19], (const float*)d_in[22],
                           (const float*)d_in[25], (const float*)d_in[28]};
    const float* w_c1 = (const float*)d_in[30];
    const float* b_c1 = (const float*)d_in[31];
    const float* w_c2 = (const float*)d_in[32];
    const float* b_c2 = (const float*)d_in[33];
    const float* w_c3 = (const float*)d_in[34];
    const float* b_c3 = (const float*)d_in[35];

    // ---- workspace layout (CL bf16 activations), ~164 MB
    short* sA  = (short*)d_ws;          // 16,777,216
    short* sB  = sA + 16777216;         // 16,777,216
    short* sk0 = sB + 16777216;         // 16,777,216 (8,256,256,32)
    short* sk1 = sk0 + 16777216;        //  8,388,608 (8,128,128,64)
    short* sk2 = sk1 + 8388608;         //  4,194,304 (8,64,64,128)
    short* sk3 = sk2 + 4194304;         //  2,097,152 (8,32,32,256)
    short* wm_d1 = sk3 + 2097152;       //    147,456
    short* wm_d2 = wm_d1 + 147456;      //    589,824
    short* wm_d3 = wm_d2 + 589824;      //  2,359,296
    short* wm_lat = wm_d3 + 2359296;    //  4,718,592
    short* wm_u0 = wm_lat + 4718592;    //  4,718,592
    short* wm_u1 = wm_u0 + 4718592;     //  1,179,648
    short* wm_u2 = wm_u1 + 1179648;     //    294,912
    short* wm_u3 = wm_u2 + 294912;      //    147,456
    float2* cplx = (float2*)(wm_u3 + 147456);  // 524,288 float2
    float2* stA = cplx + 524288;               // 8 buckets x 7,936 float2
    float* eff = (float*)(stA + 8 * STST);     // 64

    // per-layer stat slices (bucket 0 base; buckets at +k*STST)
    float2* st_d0 = stA + 0;
    float2* st_d1 = stA + 256;
    float2* st_d2 = stA + 768;
    float2* st_d3 = stA + 1792;
    float2* st_lat = stA + 3840;
    float2* st_u0 = stA + 5888;
    float2* st_u1 = stA + 6912;
    float2* st_u2 = stA + 7424;
    float2* st_u3 = stA + 7680;

    const float i64k = 1.f / 65536.f, i16k = 1.f / 16384.f, i4k = 1.f / 4096.f,
                i1k = 1.f / 1024.f, i256 = 1.f / 256.f;

    dim3 blk(256);

    // ---- fused setup: wm + eff + stat zeroing, one launch
    SetupJobs jobs;
    const float* Wl[8]  = {W_d[1], W_d[2], W_d[3], W_lat, W_u[0], W_u[1], W_u[2], W_u[3]};
    const float* Ml[8]  = {mod_d[1], mod_d[2], mod_d[3], mod_lat, mod_u[0], mod_u[1], mod_u[2], mod_u[3]};
    short* WMl[8] = {wm_d1, wm_d2, wm_d3, wm_lat, wm_u0, wm_u1, wm_u2, wm_u3};
    int Col[8] = {64, 128, 256, 256, 128, 64, 32, 32};
    int Cil[8] = {32, 64, 128, 256, 512, 256, 128, 64};
    jobs.cum[0] = 0;
    for (int l = 0; l < 8; ++l) {
        jobs.W[l] = Wl[l]; jobs.mod[l] = Ml[l]; jobs.wm[l] = WMl[l];
        jobs.Co[l] = Col[l]; jobs.Ci[l] = Cil[l];
        jobs.cum[l + 1] = jobs.cum[l] + 8 * Col[l] * Cil[l];
    }
    jobs.w1 = w_c1; jobs.b1 = b_c1; jobs.w2 = w_c2; jobs.b2 = b_c2;
    jobs.w3 = w_c3; jobs.b3 = b_c3;
    jobs.eff = eff;
    jobs.stats = (float*)stA;
    jobs.statN = 8 * STST * 2;
    jobs.wmBlocks = (jobs.cum[8] + 255) / 256;
    int setupGrid = jobs.wmBlocks + 1 + (jobs.statN + 255) / 256;
    setup_all<<<setupGrid, blk, 0, stream>>>(jobs);

    // ---- down path
    conv_d0_cl<<<dim3(256, 8), blk, 0, stream>>>(x0, W_d[0], mod_d[0], sk0, st_d0);
    maxpool_cl<<<2048, blk, 0, stream>>>(sk0, st_d0, i64k, sA, 2, 7, 7, 524288);

    conv3x3_cl<4, 4, false><<<512, blk, 0, stream>>>(sA, 32, sA, stA, 0.f, wm_d1, sk1, st_d1, 32, 64, 128, 128);
    maxpool_cl<<<1024, blk, 0, stream>>>(sk1, st_d1, i16k, sA, 3, 6, 6, 262144);

    conv3x3_cl<2, 4, false><<<512, blk, 0, stream>>>(sA, 64, sA, stA, 0.f, wm_d2, sk2, st_d2, 64, 128, 64, 64);
    maxpool_cl<<<512, blk, 0, stream>>>(sk2, st_d2, i4k, sA, 4, 5, 5, 131072);

    conv3x3_cl<2, 2, false><<<512, blk, 0, stream>>>(sA, 128, sA, stA, 0.f, wm_d3, sk3, st_d3, 128, 256, 32, 32);
    maxpool_cl<<<256, blk, 0, stream>>>(sk3, st_d3, i1k, sA, 5, 4, 4, 65536);

    conv3x3_cl<2, 1, false><<<256, blk, 0, stream>>>(sA, 256, sA, stA, 0.f, wm_lat, sB, st_lat, 256, 256, 16, 16);

    // ---- up path
    upsample_cl<<<1024, blk, 0, stream>>>(sB, st_lat, i256, sA, 5, 4, 4, 262144);
    conv3x3_cl<2, 1, false><<<512, blk, 0, stream>>>(sA, 256, sk3, stA, 0.f, wm_u0, sB, st_u0, 512, 128, 32, 32);
    conv3x3_cl<2, 2, true><<<512, blk, 0, stream>>>(sB, 128, sk2, st_u0, i1k, wm_u1, sA, st_u1, 256, 64, 64, 64);
    conv3x3_cl<4, 2, true><<<512, blk, 0, stream>>>(sA, 64, sk1, st_u1, i4k, wm_u2, sB, st_u2, 128, 32, 128, 128);
    conv3x3_cl<4, 2, true><<<2048, blk, 0, stream>>>(sB, 32, sk0, st_u2, i16k, wm_u3, sA, st_u3, 64, 32, 256, 256);

    // ---- fused norm(u3) + 1x1 chain + residual + row FFT
    final_fft_rows<<<2048, 64, 0, stream>>>(sA, st_u3, i64k, x0, eff, cplx);

    // ---- FFT data consistency (8 columns per block, coalesced)
    fft_cols_combine8<<<256, blk, 0, stream>>>(cplx, ksp, mask);
    fft_rows_inv<<<2048, 64, 0, stream>>>(cplx, (float*)d_out);
}

// Round 14
// 441.244 us; speedup vs baseline: 1.0551x; 1.0551x over previous
//
#include <hip/hip_runtime.h>

// ---------------------------------------------------------------------------
// UnetMACReconNet: modulated-conv UNet + IN/ReLU + FFT data consistency
// Round 14: aT[9] tap-prefetch gated to NCOG==1 only (lat/u0 — the VGPR=20
//           zero-ILP kernels). NCOG==2 (u1/u2/u3) reverted to R12 path.
// ---------------------------------------------------------------------------

#define EPS_IN 1e-5f
constexpr int STST = 7936;   // float2 stride between stat buckets

typedef __attribute__((ext_vector_type(8))) short short8;
typedef __attribute__((ext_vector_type(4))) short short4_t;
typedef __attribute__((ext_vector_type(4))) float f32x4;

__device__ __forceinline__ short f2bf(float f) {
    unsigned u = __float_as_uint(f);
    unsigned r = (u + 0x7fffu + ((u >> 16) & 1u)) >> 16;
    return (short)r;
}
__device__ __forceinline__ float bf2f(short s) {
    return __uint_as_float(((unsigned)(unsigned short)s) << 16);
}

// ---------------- fused setup: modded weights + eff1x1 + stat zeroing -------
struct SetupJobs {
    const float* W[8];
    const float* mod[8];
    short* wm[8];
    int Co[8];
    int Ci[8];
    int cum[9];
    const float *w1, *b1, *w2, *b2, *w3, *b3;
    float* eff;
    float* stats;
    int statN;
    int wmBlocks;
};

__global__ void setup_all(SetupJobs j)
{
    const int bx = blockIdx.x, tid = threadIdx.x;
    if (bx < j.wmBlocks) {
        int idx = bx * 256 + tid;
        if (idx >= j.cum[8]) return;
        int l = 0;
        while (idx >= j.cum[l + 1]) ++l;
        int local = idx - j.cum[l];
        const int Ci = j.Ci[l], Co = j.Co[l];
        int ci = local % Ci;
        int rem = local / Ci;
        int co = rem % Co;
        int b = rem / Co;
        const float* wp = j.W[l] + (size_t)(co * Ci + ci) * 9;
        const float* mp = j.mod[l] + ((size_t)((size_t)b * Co + co) * Ci + ci) * 9;
        short* wm = j.wm[l];
#pragma unroll
        for (int k = 0; k < 9; ++k)
            wm[(((size_t)(b * 9 + k) * Co + co) * Ci + ci)] = f2bf(wp[k] * mp[k]);
    } else if (bx == j.wmBlocks) {
        if (tid < 32) {
            float s = 0.f;
            for (int k = 0; k < 16; ++k) s += j.w2[k] * j.w1[k * 32 + tid];
            j.eff[tid] = j.w3[0] * s;
        }
        if (tid == 32) {
            float s = 0.f;
            for (int k = 0; k < 16; ++k) s += j.w2[k] * j.b1[k];
            j.eff[32] = j.w3[0] * (s + j.b2[0]) + j.b3[0];
        }
    } else {
        int i = (bx - j.wmBlocks - 1) * 256 + tid;
        if (i < j.statN) j.stats[i] = 0.f;
    }
}

// ---------------- MFMA conv3x3, CL, fused IN-stats; optional fused upsample -
template <int VR, int NCOG, bool UP>
__global__ __launch_bounds__(256) void conv3x3_cl(
    const short* __restrict__ x1, int Ci1,
    const short* __restrict__ x2,
    const float2* __restrict__ st1, float invHW1,
    const short* __restrict__ wm,   // [b][9][Co][Ci] bf16
    short* __restrict__ y,
    float2* __restrict__ stats,
    int Ci, int Co, int H, int W)
{
    constexpr int TH = 4 * VR, SH = TH + 2, SW = 18;
    constexpr int STN = UP ? 128 : 1;
    constexpr int LH = UP ? (TH / 2 + 2) : 1;
    constexpr int LW = 10, LRW = LW * 8;
    constexpr bool DW = (TH * 16 * NCOG * 16) <= (SH * SW * 32);
    __shared__ __align__(16) short s_x[SH][SW][32];
    __shared__ float s_red[4][4][NCOG][4][2];
    __shared__ float2 s_st1[STN];
    __shared__ __align__(16) short s_lr[UP ? 4 : 1][LH][LRW];

    const int tid = threadIdx.x;
    const int lane = tid & 63, wv = tid >> 6;
    const int m = lane & 15, g = lane >> 4;

    const int b = blockIdx.x & 7;
    int r = blockIdx.x >> 3;
    const int nCoB = Co / (16 * NCOG);
    const int coblk = r % nCoB;
    const int tileId = r / nCoB;
    const int tilesx = W >> 4;
    const int tx0 = (tileId % tilesx) * 16;
    const int ty0 = (tileId / tilesx) * TH;
    const int co0 = coblk * (16 * NCOG);
    const int Ci2 = Ci - Ci1;
    const int Hs = H >> 1, Ws = W >> 1;
    const int bucket = tileId & 7;

    if (UP) {
        for (int i = tid; i < Ci1; i += 256) {
            float sx = 0.f, sy = 0.f;
#pragma unroll
            for (int k = 0; k < 8; ++k) {
                float2 v = st1[(size_t)k * STST + (size_t)b * Ci1 + i];
                sx += v.x; sy += v.y;
            }
            float mu = sx * invHW1;
            float var = sy * invHW1 - mu * mu;
            s_st1[i] = make_float2(mu, rsqrtf(var + EPS_IN));
        }
    }

    f32x4 acc[NCOG][VR];
#pragma unroll
    for (int cg = 0; cg < NCOG; ++cg)
#pragma unroll
        for (int rr = 0; rr < VR; ++rr) acc[cg][rr] = (f32x4)0.f;

    const short* wmb = wm + (size_t)b * 9 * Co * Ci;
    const short* x1b = x1 + (size_t)b * (UP ? (size_t)Hs * Ws : (size_t)H * W) * Ci1;
    const short* x2b = x2 + (size_t)b * H * W * Ci2;

    for (int ci0 = 0; ci0 < Ci; ci0 += 32) {
        __syncthreads();
        if (UP && ci0 < Ci1) {
            const int cb = ci0;
            const int ly0 = (ty0 >> 1) - 1, lx0 = (tx0 >> 1) - 1;
            for (int i2 = tid; i2 < 4 * LH * LW; i2 += 256) {
                int gg = i2 & 3, p2 = i2 >> 2;
                int jj = p2 / LW, ii = p2 - jj * LW;
                int sy2 = ly0 + jj; sy2 = sy2 < 0 ? 0 : (sy2 >= Hs ? Hs - 1 : sy2);
                int sx2 = lx0 + ii; sx2 = sx2 < 0 ? 0 : (sx2 >= Ws ? Ws - 1 : sx2);
                short8 v = *(const short8*)(x1b + ((size_t)sy2 * Ws + sx2) * Ci1 + cb + gg * 8);
                short8 o;
#pragma unroll
                for (int e = 0; e < 8; ++e) {
                    float2 sv = s_st1[cb + gg * 8 + e];
                    o[e] = f2bf(fmaxf(0.f, (bf2f(v[e]) - sv.x) * sv.y));
                }
                *(short8*)&s_lr[gg][jj][ii * 8] = o;
            }
            __syncthreads();
            for (int idx = tid; idx < SH * SW * 4; idx += 256) {
                int gg = idx & 3, pos = idx >> 2;
                int yy = pos / SW, xx = pos - yy * SW;
                int gy = ty0 + yy - 1, gx = tx0 + xx - 1;
                short8 v = (short8)0;
                if (gy >= 0 && gy < H && gx >= 0 && gx < W) {
                    int xk = gx >> 1, yk = gy >> 1;
                    int xo = gx & 1, yo = gy & 1;
                    int xa = xo ? xk : (xk > 0 ? xk - 1 : 0);
                    int xb = xo ? (xk + 1 < Ws ? xk + 1 : Ws - 1) : xk;
                    float wxa = xo ? 0.75f : 0.25f;
                    int ya = yo ? yk : (yk > 0 ? yk - 1 : 0);
                    int yb = yo ? (yk + 1 < Hs ? yk + 1 : Hs - 1) : yk;
                    float wya = yo ? 0.75f : 0.25f;
                    int ja = ya - ly0, jb = yb - ly0;
                    int ia = xa - lx0, ib2 = xb - lx0;
                    short8 vaa = *(const short8*)&s_lr[gg][ja][ia * 8];
                    short8 vab = *(const short8*)&s_lr[gg][ja][ib2 * 8];
                    short8 vba = *(const short8*)&s_lr[gg][jb][ia * 8];
                    short8 vbb = *(const short8*)&s_lr[gg][jb][ib2 * 8];
#pragma unroll
                    for (int e = 0; e < 8; ++e) {
                        float r0 = wxa * bf2f(vaa[e]) + (1.f - wxa) * bf2f(vab[e]);
                        float r1 = wxa * bf2f(vba[e]) + (1.f - wxa) * bf2f(vbb[e]);
                        v[e] = f2bf(wya * r0 + (1.f - wya) * r1);
                    }
                }
                *(short8*)&s_x[yy][xx][(gg ^ (xx & 3)) * 8] = v;
            }
        } else {
            const short* src; int C, cb;
            if (ci0 < Ci1) { src = x1b; C = Ci1; cb = ci0; }
            else           { src = x2b; C = Ci2; cb = ci0 - Ci1; }
            for (int idx = tid; idx < SH * SW * 4; idx += 256) {
                int gg = idx & 3, pos = idx >> 2;
                int yy = pos / SW, xx = pos - yy * SW;
                int gy = ty0 + yy - 1, gx = tx0 + xx - 1;
                short8 v = (short8)0;
                if (gy >= 0 && gy < H && gx >= 0 && gx < W)
                    v = *(const short8*)(src + ((size_t)gy * W + gx) * C + cb + gg * 8);
                *(short8*)&s_x[yy][xx][(gg ^ (xx & 3)) * 8] = v;
            }
        }
        __syncthreads();

        if constexpr (NCOG == 1) {
            // ---- batched A prefetch: 9 tap loads in flight (fixes VGPR=20
            //      zero-ILP codegen on lat/u0; do NOT apply to NCOG=2 — R13
            //      showed it balloons VGPR past the occupancy cliff there)
            short8 aT[9];
#pragma unroll
            for (int t = 0; t < 9; ++t)
                aT[t] = *(const short8*)(wmb + ((size_t)t * Co + co0 + m) * Ci + ci0 + g * 8);
#pragma unroll
            for (int t = 0; t < 9; ++t) {
                const int dy = t / 3, dx = t - 3 * (t / 3);
                const int xx = m + dx;
                const int sgo = (g ^ (xx & 3)) * 8;
#pragma unroll
                for (int rr = 0; rr < VR; ++rr) {
                    short8 bf = *(const short8*)&s_x[wv * VR + rr + dy][xx][sgo];
                    acc[0][rr] = __builtin_amdgcn_mfma_f32_16x16x32_bf16(aT[t], bf, acc[0][rr], 0, 0, 0);
                }
            }
        } else {
#pragma unroll
            for (int t = 0; t < 9; ++t) {
                const int dy = t / 3, dx = t - 3 * (t / 3);
                const short* wr = wmb + ((size_t)t * Co + co0) * Ci + ci0 + g * 8;
                short8 a[NCOG];
#pragma unroll
                for (int cg = 0; cg < NCOG; ++cg)
                    a[cg] = *(const short8*)(wr + (size_t)(cg * 16 + m) * Ci);
                const int xx = m + dx;
                const int sgo = (g ^ (xx & 3)) * 8;
#pragma unroll
                for (int rr = 0; rr < VR; ++rr) {
                    short8 bf = *(const short8*)&s_x[wv * VR + rr + dy][xx][sgo];
#pragma unroll
                    for (int cg = 0; cg < NCOG; ++cg)
                        acc[cg][rr] = __builtin_amdgcn_mfma_f32_16x16x32_bf16(a[cg], bf, acc[cg][rr], 0, 0, 0);
                }
            }
        }
    }

    // ---- writeout
    if constexpr (DW) {
        __syncthreads();
        short* sd = (short*)&s_x[0][0][0];   // [TH][16][NCOG*16]
#pragma unroll
        for (int cg = 0; cg < NCOG; ++cg)
#pragma unroll
            for (int rr = 0; rr < VR; ++rr) {
                short4_t o;
#pragma unroll
                for (int q = 0; q < 4; ++q) o[q] = f2bf(acc[cg][rr][q]);
                *(short4_t*)&sd[((wv * VR + rr) * 16 + m) * (NCOG * 16) + cg * 16 + g * 4] = o;
            }
        __syncthreads();
        constexpr int N16 = TH * 16 * NCOG * 2;
        constexpr int CPR = NCOG * 32;
        for (int c = tid; c < N16; c += 256) {
            int row = c / CPR;
            int o16 = c % CPR;
            int p = o16 / (NCOG * 2);
            int cw = o16 % (NCOG * 2);
            short8 v = *(short8*)&sd[(row * 16 + p) * (NCOG * 16) + cw * 8];
            *(short8*)(y + (((size_t)b * H + ty0 + row) * W + tx0 + p) * Co + co0 + cw * 8) = v;
        }
    } else {
        const int ox = tx0 + m;
#pragma unroll
        for (int cg = 0; cg < NCOG; ++cg)
#pragma unroll
            for (int rr = 0; rr < VR; ++rr) {
                int oy = ty0 + wv * VR + rr;
                short4_t o;
#pragma unroll
                for (int q = 0; q < 4; ++q) o[q] = f2bf(acc[cg][rr][q]);
                *(short4_t*)(y + (((size_t)b * H + oy) * W + ox) * Co + co0 + cg * 16 + g * 4) = o;
            }
    }

    // ---- fused stats (bucketed atomics)
#pragma unroll
    for (int cg = 0; cg < NCOG; ++cg)
#pragma unroll
        for (int q = 0; q < 4; ++q) {
            float s = 0.f, s2 = 0.f;
#pragma unroll
            for (int rr = 0; rr < VR; ++rr) { float v = acc[cg][rr][q]; s += v; s2 += v * v; }
#pragma unroll
            for (int msk = 1; msk < 16; msk <<= 1) { s += __shfl_xor(s, msk); s2 += __shfl_xor(s2, msk); }
            if (m == 0) { s_red[wv][g][cg][q][0] = s; s_red[wv][g][cg][q][1] = s2; }
        }
    __syncthreads();
    for (int i = tid; i < 16 * NCOG; i += 256) {
        int q = i & 3, gg = (i >> 2) & 3, cg = i >> 4;
        float S = 0.f, S2 = 0.f;
#pragma unroll
        for (int w = 0; w < 4; ++w) { S += s_red[w][gg][cg][q][0]; S2 += s_red[w][gg][cg][q][1]; }
        float* sp = (float*)&stats[(size_t)bucket * STST + (size_t)b * Co + co0 + i];
        atomicAdd(sp, S); atomicAdd(sp + 1, S2);
    }
}

// ---------------- d0 conv: Ci=1, Co=32, fp32 NCHW in -> CL bf16 raw out -----
__global__ __launch_bounds__(256) void conv_d0_cl(
    const float* __restrict__ x0, const float* __restrict__ W,
    const float* __restrict__ mod, short* __restrict__ y,
    float2* __restrict__ stats)
{
    __shared__ float s[18][18];
    __shared__ float sw[32][9];
    __shared__ float s_red[8][32][2];
    __shared__ __align__(16) short sd[16][16][32];
    const int tid = threadIdx.x;
    const int tx = tid & 15, ty = tid >> 4;
    const int tx0 = (blockIdx.x & 15) * 16, ty0 = (blockIdx.x >> 4) * 16;
    const int b = blockIdx.y;
    if (tid < 288) sw[tid / 9][tid % 9] = W[tid] * mod[b * 288 + tid];
    for (int pos = tid; pos < 18 * 18; pos += 256) {
        int yy = pos / 18, xx = pos - yy * 18;
        int gy = ty0 + yy - 1, gx = tx0 + xx - 1;
        bool inb = gy >= 0 && gy < 256 && gx >= 0 && gx < 256;
        s[yy][xx] = inb ? x0[((size_t)b << 16) + gy * 256 + gx] : 0.f;
    }
    __syncthreads();
    float v[3][3];
#pragma unroll
    for (int r = 0; r < 3; ++r)
#pragma unroll
        for (int c = 0; c < 3; ++c) v[r][c] = s[ty + r][tx + c];
    float vals[32];
#pragma unroll
    for (int co = 0; co < 32; ++co) {
        float a = 0.f;
#pragma unroll
        for (int r = 0; r < 3; ++r)
#pragma unroll
            for (int c = 0; c < 3; ++c) a = fmaf(v[r][c], sw[co][r * 3 + c], a);
        vals[co] = a;
    }
#pragma unroll
    for (int j = 0; j < 4; ++j) {
        short8 o;
#pragma unroll
        for (int e = 0; e < 8; ++e) o[e] = f2bf(vals[j * 8 + e]);
        *(short8*)&sd[ty][tx][j * 8] = o;
    }
    __syncthreads();
    for (int c = tid; c < 1024; c += 256) {
        int row = c >> 6, o = c & 63;
        short8 vv = *(short8*)&sd[row][o >> 2][(o & 3) * 8];
        *(short8*)(y + (((size_t)b * 256 + ty0 + row) * 256 + tx0 + (o >> 2)) * 32 + (o & 3) * 8) = vv;
    }
    {
        const int c = tid & 31, grp = tid >> 5;
        const short* sdf = (const short*)sd;
        float ss = 0.f, ss2 = 0.f;
#pragma unroll
        for (int p = 0; p < 32; ++p) {
            float vv = bf2f(sdf[(grp * 32 + p) * 32 + c]);
            ss += vv; ss2 += vv * vv;
        }
        s_red[grp][c][0] = ss;
        s_red[grp][c][1] = ss2;
    }
    __syncthreads();
    if (tid < 32) {
        float S = 0.f, S2 = 0.f;
#pragma unroll
        for (int g2 = 0; g2 < 8; ++g2) { S += s_red[g2][tid][0]; S2 += s_red[g2][tid][1]; }
        int bucket = blockIdx.x & 7;
        float* sp = (float*)&stats[(size_t)bucket * STST + (size_t)b * 32 + tid];
        atomicAdd(sp, S); atomicAdd(sp + 1, S2);
    }
}

// ---------------- 2x2 maxpool + fused norm/relu + normalized skip writeback -
__global__ __launch_bounds__(256) void maxpool_cl(
    short* __restrict__ in, const float2* __restrict__ st, float invHW,
    short* __restrict__ out, int c8s, int ws, int hs, int total8)
{
    const int C = 8 << c8s;
    __shared__ float2 sst[2048];
    for (int i = threadIdx.x; i < 8 * C; i += 256) {
        int bb = i / C, c = i % C;
        float sx = 0.f, sy = 0.f;
#pragma unroll
        for (int k = 0; k < 8; ++k) {
            float2 v = st[(size_t)k * STST + (size_t)bb * C + c];
            sx += v.x; sy += v.y;
        }
        float mu = sx * invHW;
        sst[i] = make_float2(mu, rsqrtf(sy * invHW - mu * mu + EPS_IN));
    }
    __syncthreads();
    for (int idx = blockIdx.x * 256 + threadIdx.x; idx < total8; idx += gridDim.x * 256) {
        int c8 = idx & ((1 << c8s) - 1);
        int p = idx >> c8s;
        int x = p & ((1 << ws) - 1);
        int yy = (p >> ws) & ((1 << hs) - 1);
        int b = p >> (ws + hs);
        short* ip = in + (((size_t)b * (2 << hs) + 2 * yy) * (2 << ws) + 2 * x) * C + c8 * 8;
        size_t rs = (size_t)(2 << ws) * C;
        short8 v0 = *(const short8*)ip, v1 = *(const short8*)(ip + C);
        short8 v2 = *(const short8*)(ip + rs), v3 = *(const short8*)(ip + rs + C);
        short8 o, w0, w1, w2, w3;
#pragma unroll
        for (int e = 0; e < 8; ++e) {
            float2 sv = sst[b * C + c8 * 8 + e];
            float n0 = fmaxf(0.f, (bf2f(v0[e]) - sv.x) * sv.y);
            float n1 = fmaxf(0.f, (bf2f(v1[e]) - sv.x) * sv.y);
            float n2 = fmaxf(0.f, (bf2f(v2[e]) - sv.x) * sv.y);
            float n3 = fmaxf(0.f, (bf2f(v3[e]) - sv.x) * sv.y);
            w0[e] = f2bf(n0); w1[e] = f2bf(n1); w2[e] = f2bf(n2); w3[e] = f2bf(n3);
            o[e] = f2bf(fmaxf(fmaxf(n0, n1), fmaxf(n2, n3)));
        }
        *(short8*)ip = w0;
        *(short8*)(ip + C) = w1;
        *(short8*)(ip + rs) = w2;
        *(short8*)(ip + rs + C) = w3;
        *(short8*)(out + (size_t)idx * 8) = o;
    }
}

// ---------------- bilinear 2x upsample + fused norm/relu (u0 source only) ---
__global__ __launch_bounds__(256) void upsample_cl(
    const short* __restrict__ in, const float2* __restrict__ st, float invHW,
    short* __restrict__ out, int c8s, int wsi, int hsi, int total8)
{
    const int C = 8 << c8s;
    const int Win = 1 << wsi, Hin = 1 << hsi;
    __shared__ float2 sst[2048];
    for (int i = threadIdx.x; i < 8 * C; i += 256) {
        int bb = i / C, c = i % C;
        float sx = 0.f, sy = 0.f;
#pragma unroll
        for (int k = 0; k < 8; ++k) {
            float2 v = st[(size_t)k * STST + (size_t)bb * C + c];
            sx += v.x; sy += v.y;
        }
        float mu = sx * invHW;
        sst[i] = make_float2(mu, rsqrtf(sy * invHW - mu * mu + EPS_IN));
    }
    __syncthreads();
    for (int idx = blockIdx.x * 256 + threadIdx.x; idx < total8; idx += gridDim.x * 256) {
        int c8 = idx & ((1 << c8s) - 1);
        int p = idx >> c8s;
        int x = p & (2 * Win - 1);
        int yy = (p >> (wsi + 1)) & (2 * Hin - 1);
        int b = p >> (wsi + 1 + hsi + 1);
        int xk = x >> 1, yk = yy >> 1;
        int xa, xb; float wxa;
        if (x & 1) { xa = xk; xb = (xk + 1 < Win) ? xk + 1 : Win - 1; wxa = 0.75f; }
        else       { xa = (xk > 0) ? xk - 1 : 0; xb = xk; wxa = 0.25f; }
        int ya, yb; float wya;
        if (yy & 1) { ya = yk; yb = (yk + 1 < Hin) ? yk + 1 : Hin - 1; wya = 0.75f; }
        else        { ya = (yk > 0) ? yk - 1 : 0; yb = yk; wya = 0.25f; }
        const short* ib = in + (size_t)b * Hin * Win * C + c8 * 8;
        short8 vaa = *(const short8*)(ib + ((size_t)ya * Win + xa) * C);
        short8 vab = *(const short8*)(ib + ((size_t)ya * Win + xb) * C);
        short8 vba = *(const short8*)(ib + ((size_t)yb * Win + xa) * C);
        short8 vbb = *(const short8*)(ib + ((size_t)yb * Win + xb) * C);
        short8 o;
#pragma unroll
        for (int e = 0; e < 8; ++e) {
            float2 sv = sst[b * C + c8 * 8 + e];
            float aa = fmaxf(0.f, (bf2f(vaa[e]) - sv.x) * sv.y);
            float ab = fmaxf(0.f, (bf2f(vab[e]) - sv.x) * sv.y);
            float ba = fmaxf(0.f, (bf2f(vba[e]) - sv.x) * sv.y);
            float bb = fmaxf(0.f, (bf2f(vbb[e]) - sv.x) * sv.y);
            float r0 = wxa * aa + (1.f - wxa) * ab;
            float r1 = wxa * ba + (1.f - wxa) * bb;
            o[e] = f2bf(wya * r0 + (1.f - wya) * r1);
        }
        *(short8*)(out + (size_t)idx * 8) = o;
    }
}

// ---------------- 256-point radix-2 FFT in LDS (one wave) -------------------
__device__ __forceinline__ void fft256(float2* s, int tid, float sign)
{
    __syncthreads();
#pragma unroll
    for (int t = 0; t < 4; ++t) {
        int i = tid + t * 64;
        int r = __brev(i) >> 24;
        if (r > i) { float2 tmp = s[i]; s[i] = s[r]; s[r] = tmp; }
    }
    __syncthreads();
    for (int st = 1; st <= 8; ++st) {
        int m = 1 << st, half = m >> 1;
#pragma unroll
        for (int t = 0; t < 2; ++t) {
            int k = tid + t * 64;
            int g = k >> (st - 1), j = k & (half - 1);
            int i0 = (g << st) + j, i1 = i0 + half;
            float ang = sign * 6.283185307179586f * (float)j / (float)m;
            float sn, cs;
            __sincosf(ang, &sn, &cs);
            float2 a = s[i0], b = s[i1];
            float2 tt = make_float2(b.x * cs - b.y * sn, b.x * sn + b.y * cs);
            s[i0] = make_float2(a.x + tt.x, a.y + tt.y);
            s[i1] = make_float2(a.x - tt.x, a.y - tt.y);
        }
        __syncthreads();
    }
}

// ---------------- fused: norm(u3) + 1x1 chain + residual + row FFT ----------
__global__ __launch_bounds__(64) void final_fft_rows(
    const short* __restrict__ act, const float2* __restrict__ st, float invHW,
    const float* __restrict__ x0, const float* __restrict__ eff,
    float2* __restrict__ cplx)
{
    __shared__ float2 s[256];
    __shared__ float2 sst[32];
    __shared__ float seff[33];
    const int row = blockIdx.x, tid = threadIdx.x;
    const int b = row >> 8, yy = row & 255;
    if (tid < 32) {
        float sx = 0.f, sy = 0.f;
#pragma unroll
        for (int k = 0; k < 8; ++k) {
            float2 v = st[(size_t)k * STST + (size_t)b * 32 + tid];
            sx += v.x; sy += v.y;
        }
        float mu = sx * invHW;
        sst[tid] = make_float2(mu, rsqrtf(sy * invHW - mu * mu + EPS_IN));
    }
    if (tid < 33) seff[tid] = eff[tid];
    __syncthreads();
#pragma unroll
    for (int k = 0; k < 4; ++k) {
        int x = k * 64 + tid;
        const short8* a = (const short8*)(act + (((size_t)b * 256 + yy) * 256 + x) * 32);
        float sacc = seff[32] + x0[((size_t)b << 16) + (yy << 8) + x];
#pragma unroll
        for (int j = 0; j < 4; ++j) {
            short8 v = a[j];
#pragma unroll
            for (int e = 0; e < 8; ++e) {
                float2 sv = sst[j * 8 + e];
                sacc += seff[j * 8 + e] * fmaxf(0.f, (bf2f(v[e]) - sv.x) * sv.y);
            }
        }
        s[x] = make_float2(sacc, 0.f);
    }
    fft256(s, tid, -1.f);
    float2* o = cplx + (size_t)row * 256;
    for (int i = tid; i < 256; i += 64) o[i] = s[i];
}

// ---------------- column FFT + combine: 8 columns per 256-thread block ------
__global__ __launch_bounds__(256) void fft_cols_combine8(
    float2* __restrict__ data, const float* __restrict__ ksp,
    const float* __restrict__ mask)
{
    __shared__ float2 s2[8][260];
    const int tid = threadIdx.x;
    const int b = blockIdx.x >> 5;
    const int col0 = (blockIdx.x & 31) * 8;
    float2* base = data + (size_t)b * 65536 + col0;
    for (int idx = tid; idx < 2048; idx += 256) {
        int row = idx >> 3, c = idx & 7;
        s2[c][row] = base[row * 256 + c];
    }
    __syncthreads();
    const int c = tid >> 5, lt = tid & 31;
#pragma unroll
    for (int t = 0; t < 8; ++t) {
        int i = lt + t * 32;
        int r = __brev(i) >> 24;
        if (r > i) { float2 tmp = s2[c][i]; s2[c][i] = s2[c][r]; s2[c][r] = tmp; }
    }
    __syncthreads();
    for (int st = 1; st <= 8; ++st) {
        int m = 1 << st, half = m >> 1;
#pragma unroll
        for (int t = 0; t < 4; ++t) {
            int k = lt + t * 32;
            int g = k >> (st - 1), j = k & (half - 1);
            int i0 = (g << st) + j, i1 = i0 + half;
            float ang = -6.283185307179586f * (float)j / (float)m;
            float sn, cs;
            __sincosf(ang, &sn, &cs);
            float2 a = s2[c][i0], bb = s2[c][i1];
            float2 tt = make_float2(bb.x * cs - bb.y * sn, bb.x * sn + bb.y * cs);
            s2[c][i0] = make_float2(a.x + tt.x, a.y + tt.y);
            s2[c][i1] = make_float2(a.x - tt.x, a.y - tt.y);
        }
        __syncthreads();
    }
    for (int idx = tid; idx < 2048; idx += 256) {
        int row = idx >> 3, cc = idx & 7;
        size_t mi = ((size_t)b * 256 + row) * 256 + col0 + cc;
        float mval = mask[mi];
        float2 kp = s2[cc][row];
        float kr = ksp[mi * 2], ki = ksp[mi * 2 + 1];
        s2[cc][row] = make_float2(mval * kr + (1.f - mval) * kp.x * (1.f / 256.f),
                                  mval * ki + (1.f - mval) * kp.y * (1.f / 256.f));
    }
    __syncthreads();
#pragma unroll
    for (int t = 0; t < 8; ++t) {
        int i = lt + t * 32;
        int r = __brev(i) >> 24;
        if (r > i) { float2 tmp = s2[c][i]; s2[c][i] = s2[c][r]; s2[c][r] = tmp; }
    }
    __syncthreads();
    for (int st = 1; st <= 8; ++st) {
        int m = 1 << st, half = m >> 1;
#pragma unroll
        for (int t = 0; t < 4; ++t) {
            int k = lt + t * 32;
            int g = k >> (st - 1), j = k & (half - 1);
            int i0 = (g << st) + j, i1 = i0 + half;
            float ang = 6.283185307179586f * (float)j / (float)m;
            float sn, cs;
            __sincosf(ang, &sn, &cs);
            float2 a = s2[c][i0], bb = s2[c][i1];
            float2 tt = make_float2(bb.x * cs - bb.y * sn, bb.x * sn + bb.y * cs);
            s2[c][i0] = make_float2(a.x + tt.x, a.y + tt.y);
            s2[c][i1] = make_float2(a.x - tt.x, a.y - tt.y);
        }
        __syncthreads();
    }
    for (int idx = tid; idx < 2048; idx += 256) {
        int row = idx >> 3, cc = idx & 7;
        base[row * 256 + cc] = s2[cc][row];
    }
}

__global__ __launch_bounds__(64) void fft_rows_inv(const float2* __restrict__ data,
                                                   float* __restrict__ out)
{
    __shared__ float2 s[256];
    int row = blockIdx.x, tid = threadIdx.x;
    const float2* p = data + (size_t)row * 256;
    for (int i = tid; i < 256; i += 64) s[i] = p[i];
    fft256(s, tid, 1.f);
    float* o = out + (size_t)row * 256;
    for (int i = tid; i < 256; i += 64) o[i] = s[i].x * (1.f / 256.f);
}

// ---------------------------------------------------------------------------
extern "C" void kernel_launch(void* const* d_in, const int* in_sizes, int n_in,
                              void* d_out, int out_size, void* d_ws, size_t ws_size,
                              hipStream_t stream)
{
    (void)in_sizes; (void)n_in; (void)out_size; (void)ws_size;

    const float* x0 = (const float*)d_in[0];
    const float* ksp = (const float*)d_in[1];
    const float* mask = (const float*)d_in[2];
    const float* mod_d[4] = {(const float*)d_in[3], (const float*)d_in[6],
                             (const float*)d_in[9], (const float*)d_in[12]};
    const float* W_d[4] = {(const float*)d_in[4], (const float*)d_in[7],
                           (const float*)d_in[10], (const float*)d_in[13]};
    const float* mod_lat = (const float*)d_in[15];
    const float* W_lat = (const float*)d_in[16];
    const float* mod_u[4] = {(const float*)d_in[18], (const float*)d_in[21],
                             (const float*)d_in[24], (const float*)d_in[27]};
    const float* W_u[4] = {(const float*)d_in[19], (const float*)d_in[22],
                           (const float*)d_in[25], (const float*)d_in[28]};
    const float* w_c1 = (const float*)d_in[30];
    const float* b_c1 = (const float*)d_in[31];
    const float* w_c2 = (const float*)d_in[32];
    const float* b_c2 = (const float*)d_in[33];
    const float* w_c3 = (const float*)d_in[34];
    const float* b_c3 = (const float*)d_in[35];

    // ---- workspace layout (CL bf16 activations), ~164 MB
    short* sA  = (short*)d_ws;          // 16,777,216
    short* sB  = sA + 16777216;         // 16,777,216
    short* sk0 = sB + 16777216;         // 16,777,216 (8,256,256,32)
    short* sk1 = sk0 + 16777216;        //  8,388,608 (8,128,128,64)
    short* sk2 = sk1 + 8388608;         //  4,194,304 (8,64,64,128)
    short* sk3 = sk2 + 4194304;         //  2,097,152 (8,32,32,256)
    short* wm_d1 = sk3 + 2097152;       //    147,456
    short* wm_d2 = wm_d1 + 147456;      //    589,824
    short* wm_d3 = wm_d2 + 589824;      //  2,359,296
    short* wm_lat = wm_d3 + 2359296;    //  4,718,592
    short* wm_u0 = wm_lat + 4718592;    //  4,718,592
    short* wm_u1 = wm_u0 + 4718592;     //  1,179,648
    short* wm_u2 = wm_u1 + 1179648;     //    294,912
    short* wm_u3 = wm_u2 + 294912;      //    147,456
    float2* cplx = (float2*)(wm_u3 + 147456);  // 524,288 float2
    float2* stA = cplx + 524288;               // 8 buckets x 7,936 float2
    float* eff = (float*)(stA + 8 * STST);     // 64

    // per-layer stat slices (bucket 0 base; buckets at +k*STST)
    float2* st_d0 = stA + 0;
    float2* st_d1 = stA + 256;
    float2* st_d2 = stA + 768;
    float2* st_d3 = stA + 1792;
    float2* st_lat = stA + 3840;
    float2* st_u0 = stA + 5888;
    float2* st_u1 = stA + 6912;
    float2* st_u2 = stA + 7424;
    float2* st_u3 = stA + 7680;

    const float i64k = 1.f / 65536.f, i16k = 1.f / 16384.f, i4k = 1.f / 4096.f,
                i1k = 1.f / 1024.f, i256 = 1.f / 256.f;

    dim3 blk(256);

    // ---- fused setup: wm + eff + stat zeroing, one launch
    SetupJobs jobs;
    const float* Wl[8]  = {W_d[1], W_d[2], W_d[3], W_lat, W_u[0], W_u[1], W_u[2], W_u[3]};
    const float* Ml[8]  = {mod_d[1], mod_d[2], mod_d[3], mod_lat, mod_u[0], mod_u[1], mod_u[2], mod_u[3]};
    short* WMl[8] = {wm_d1, wm_d2, wm_d3, wm_lat, wm_u0, wm_u1, wm_u2, wm_u3};
    int Col[8] = {64, 128, 256, 256, 128, 64, 32, 32};
    int Cil[8] = {32, 64, 128, 256, 512, 256, 128, 64};
    jobs.cum[0] = 0;
    for (int l = 0; l < 8; ++l) {
        jobs.W[l] = Wl[l]; jobs.mod[l] = Ml[l]; jobs.wm[l] = WMl[l];
        jobs.Co[l] = Col[l]; jobs.Ci[l] = Cil[l];
        jobs.cum[l + 1] = jobs.cum[l] + 8 * Col[l] * Cil[l];
    }
    jobs.w1 = w_c1; jobs.b1 = b_c1; jobs.w2 = w_c2; jobs.b2 = b_c2;
    jobs.w3 = w_c3; jobs.b3 = b_c3;
    jobs.eff = eff;
    jobs.stats = (float*)stA;
    jobs.statN = 8 * STST * 2;
    jobs.wmBlocks = (jobs.cum[8] + 255) / 256;
    int setupGrid = jobs.wmBlocks + 1 + (jobs.statN + 255) / 256;
    setup_all<<<setupGrid, blk, 0, stream>>>(jobs);

    // ---- down path
    conv_d0_cl<<<dim3(256, 8), blk, 0, stream>>>(x0, W_d[0], mod_d[0], sk0, st_d0);
    maxpool_cl<<<2048, blk, 0, stream>>>(sk0, st_d0, i64k, sA, 2, 7, 7, 524288);

    conv3x3_cl<4, 4, false><<<512, blk, 0, stream>>>(sA, 32, sA, stA, 0.f, wm_d1, sk1, st_d1, 32, 64, 128, 128);
    maxpool_cl<<<1024, blk, 0, stream>>>(sk1, st_d1, i16k, sA, 3, 6, 6, 262144);

    conv3x3_cl<2, 4, false><<<512, blk, 0, stream>>>(sA, 64, sA, stA, 0.f, wm_d2, sk2, st_d2, 64, 128, 64, 64);
    maxpool_cl<<<512, blk, 0, stream>>>(sk2, st_d2, i4k, sA, 4, 5, 5, 131072);

    conv3x3_cl<2, 2, false><<<512, blk, 0, stream>>>(sA, 128, sA, stA, 0.f, wm_d3, sk3, st_d3, 128, 256, 32, 32);
    maxpool_cl<<<256, blk, 0, stream>>>(sk3, st_d3, i1k, sA, 5, 4, 4, 65536);

    conv3x3_cl<2, 1, false><<<256, blk, 0, stream>>>(sA, 256, sA, stA, 0.f, wm_lat, sB, st_lat, 256, 256, 16, 16);

    // ---- up path
    upsample_cl<<<1024, blk, 0, stream>>>(sB, st_lat, i256, sA, 5, 4, 4, 262144);
    conv3x3_cl<2, 1, false><<<512, blk, 0, stream>>>(sA, 256, sk3, stA, 0.f, wm_u0, sB, st_u0, 512, 128, 32, 32);
    conv3x3_cl<2, 2, true><<<512, blk, 0, stream>>>(sB, 128, sk2, st_u0, i1k, wm_u1, sA, st_u1, 256, 64, 64, 64);
    conv3x3_cl<4, 2, true><<<512, blk, 0, stream>>>(sA, 64, sk1, st_u1, i4k, wm_u2, sB, st_u2, 128, 32, 128, 128);
    conv3x3_cl<4, 2, true><<<2048, blk, 0, stream>>>(sB, 32, sk0, st_u2, i16k, wm_u3, sA, st_u3, 64, 32, 256, 256);

    // ---- fused norm(u3) + 1x1 chain + residual + row FFT
    final_fft_rows<<<2048, 64, 0, stream>>>(sA, st_u3, i64k, x0, eff, cplx);

    // ---- FFT data consistency (8 columns per block, coalesced)
    fft_cols_combine8<<<256, blk, 0, stream>>>(cplx, ksp, mask);
    fft_rows_inv<<<2048, 64, 0, stream>>>(cplx, (float*)d_out);
}